// Round 1
// baseline (632.971 us; speedup 1.0000x reference)
//
#include <hip/hip_runtime.h>
#include <math.h>

#define BATCH 8
#define N 2048
#define D 256
#define K_INST 512
#define K_REL 32
#define PAIRS_PER_B (K_INST * K_REL)   // 16384

// ---------------------------------------------------------------------------
// Kernel 1: scores = q @ k^T  (per batch, 2048x2048x256, fp32)
// 128x128 block tile, BK=16, 256 threads, 8x8 micro-tile per thread.
// ---------------------------------------------------------------------------
#define BM 128
#define BN 128
#define BK 16
#define PAD 4   // LDS row padding: keeps 16B alignment, rotates banks

__global__ __launch_bounds__(256)
void gemm_qkT(const float* __restrict__ q, const float* __restrict__ kmat,
              float* __restrict__ out) {
  const int bz = blockIdx.z;
  const int row0 = blockIdx.y * BM;
  const int col0 = blockIdx.x * BN;
  const float* Q = q + (size_t)bz * N * D;
  const float* Kp = kmat + (size_t)bz * N * D;
  float* O = out + (size_t)bz * N * N;

  __shared__ float Qs[BK][BM + PAD];
  __shared__ float Ks[BK][BN + PAD];

  const int tid = threadIdx.x;
  const int lr = tid >> 2;          // 0..63  (row within tile)
  const int lc = (tid & 3) * 4;     // 0,4,8,12 (col within BK)
  const int tx = tid & 15;          // 0..15
  const int ty = tid >> 4;          // 0..15

  float acc[8][8];
#pragma unroll
  for (int i = 0; i < 8; i++)
#pragma unroll
    for (int j = 0; j < 8; j++) acc[i][j] = 0.f;

  for (int kt = 0; kt < D; kt += BK) {
    float4 a0 = *(const float4*)&Q[(size_t)(row0 + lr) * D + kt + lc];
    float4 a1 = *(const float4*)&Q[(size_t)(row0 + lr + 64) * D + kt + lc];
    float4 b0 = *(const float4*)&Kp[(size_t)(col0 + lr) * D + kt + lc];
    float4 b1 = *(const float4*)&Kp[(size_t)(col0 + lr + 64) * D + kt + lc];
    __syncthreads();  // protect LDS from previous iteration's readers
    Qs[lc + 0][lr] = a0.x; Qs[lc + 1][lr] = a0.y; Qs[lc + 2][lr] = a0.z; Qs[lc + 3][lr] = a0.w;
    Qs[lc + 0][lr + 64] = a1.x; Qs[lc + 1][lr + 64] = a1.y; Qs[lc + 2][lr + 64] = a1.z; Qs[lc + 3][lr + 64] = a1.w;
    Ks[lc + 0][lr] = b0.x; Ks[lc + 1][lr] = b0.y; Ks[lc + 2][lr] = b0.z; Ks[lc + 3][lr] = b0.w;
    Ks[lc + 0][lr + 64] = b1.x; Ks[lc + 1][lr + 64] = b1.y; Ks[lc + 2][lr + 64] = b1.z; Ks[lc + 3][lr + 64] = b1.w;
    __syncthreads();
#pragma unroll
    for (int kk = 0; kk < BK; ++kk) {
      const float4 qa = *(const float4*)&Qs[kk][ty * 8];
      const float4 qb = *(const float4*)&Qs[kk][ty * 8 + 4];
      const float4 ka = *(const float4*)&Ks[kk][tx * 8];
      const float4 kb = *(const float4*)&Ks[kk][tx * 8 + 4];
      float av[8] = {qa.x, qa.y, qa.z, qa.w, qb.x, qb.y, qb.z, qb.w};
      float bv[8] = {ka.x, ka.y, ka.z, ka.w, kb.x, kb.y, kb.z, kb.w};
#pragma unroll
      for (int i = 0; i < 8; i++)
#pragma unroll
        for (int j = 0; j < 8; j++)
          acc[i][j] = fmaf(av[i], bv[j], acc[i][j]);
    }
  }

#pragma unroll
  for (int i = 0; i < 8; i++) {
    float4 s0 = make_float4(acc[i][0], acc[i][1], acc[i][2], acc[i][3]);
    float4 s1 = make_float4(acc[i][4], acc[i][5], acc[i][6], acc[i][7]);
    float* orow = &O[(size_t)(row0 + ty * 8 + i) * N + col0 + tx * 8];
    *(float4*)orow = s0;
    *((float4*)orow + 1) = s1;
  }
}

// ---------------------------------------------------------------------------
// Kernel 2: per-row max, sum(exp), and softmax diagonal value.
// One 256-thread block per row (B*N = 16384 rows).
// ---------------------------------------------------------------------------
__global__ __launch_bounds__(256)
void row_stats(const float* __restrict__ scores, float* __restrict__ m_out,
               float* __restrict__ s_out, float* __restrict__ diag_out) {
  const int row = blockIdx.x;              // b*N + i
  const float* srow = scores + (size_t)row * N;
  const float4* r4 = (const float4*)srow;
  const int t = threadIdx.x;
  const int lane = t & 63, wid = t >> 6;
  float4 v0 = r4[t];
  float4 v1 = r4[t + 256];
  float mx = fmaxf(fmaxf(fmaxf(v0.x, v0.y), fmaxf(v0.z, v0.w)),
                   fmaxf(fmaxf(v1.x, v1.y), fmaxf(v1.z, v1.w)));
  __shared__ float redm[4], reds[4], bc[1];
#pragma unroll
  for (int o = 32; o > 0; o >>= 1) mx = fmaxf(mx, __shfl_down(mx, o));
  if (lane == 0) redm[wid] = mx;
  __syncthreads();
  if (t == 0) bc[0] = fmaxf(fmaxf(redm[0], redm[1]), fmaxf(redm[2], redm[3]));
  __syncthreads();
  const float m = bc[0];
  float s = expf(v0.x - m) + expf(v0.y - m) + expf(v0.z - m) + expf(v0.w - m)
          + expf(v1.x - m) + expf(v1.y - m) + expf(v1.z - m) + expf(v1.w - m);
#pragma unroll
  for (int o = 32; o > 0; o >>= 1) s += __shfl_down(s, o);
  if (lane == 0) reds[wid] = s;
  __syncthreads();
  if (t == 0) {
    float S = reds[0] + reds[1] + reds[2] + reds[3];
    int i = row & (N - 1);
    float sii = srow[i];
    m_out[row] = m;
    s_out[row] = S;
    diag_out[row] = expf(sii - m) / S;
  }
}

// ---------------------------------------------------------------------------
// Kernel 3: per-batch top-512 of diag (jax.lax.top_k tie-break: lower index
// first), then output the selected indices sorted ascending.
// One 256-thread block per batch. Bitonic sort of 2048 (val desc, idx asc).
// ---------------------------------------------------------------------------
__global__ __launch_bounds__(256)
void topk_inst(const float* __restrict__ diag, int* __restrict__ inst) {
  const int b = blockIdx.x;
  __shared__ float v[2048];
  __shared__ int id[2048];
  __shared__ int sel[K_INST];
  const int tid = threadIdx.x;
  for (int e = tid; e < 2048; e += 256) { v[e] = diag[b * N + e]; id[e] = e; }
  __syncthreads();
  for (int k = 2; k <= 2048; k <<= 1) {
    for (int j = k >> 1; j > 0; j >>= 1) {
      for (int p = tid; p < 1024; p += 256) {
        int i = 2 * p - (p & (j - 1));
        int ixj = i | j;
        float va = v[i], vb = v[ixj];
        int ia = id[i], ib = id[ixj];
        bool a_first = (va > vb) || (va == vb && ia < ib);  // descending order
        bool up = ((i & k) == 0);
        if (up != a_first) { v[i] = vb; v[ixj] = va; id[i] = ib; id[ixj] = ia; }
      }
      __syncthreads();
    }
  }
  for (int e = tid; e < K_INST; e += 256) sel[e] = id[e];
  __syncthreads();
  // sort the 512 selected indices ascending (bitonic, 256 pairs = 1/thread)
  for (int k = 2; k <= K_INST; k <<= 1) {
    for (int j = k >> 1; j > 0; j >>= 1) {
      int p = tid;
      int i = 2 * p - (p & (j - 1));
      int ixj = i | j;
      int a = sel[i], c = sel[ixj];
      bool a_first = a < c;           // ascending
      bool up = ((i & k) == 0);
      if (up != a_first) { sel[i] = c; sel[ixj] = a; }
      __syncthreads();
    }
  }
  for (int e = tid; e < K_INST; e += 256) inst[b * K_INST + e] = sel[e];
}

// ---------------------------------------------------------------------------
// Kernel 4: rel matrix row -> top-32 columns (tie-break lower col), columns
// sorted ascending; emit soi (as floats) and int (subj,obj) pairs for k5.
// One 256-thread block per rel row (B*512 = 4096 blocks).
// ---------------------------------------------------------------------------
__global__ __launch_bounds__(256)
void rel_topk(const float* __restrict__ scores, const float* __restrict__ m_arr,
              const float* __restrict__ s_arr, const int* __restrict__ inst,
              float* __restrict__ soi_out, int* __restrict__ pairs) {
  const int blk = blockIdx.x;
  const int b = blk >> 9;
  const int r = blk & 511;
  __shared__ float v[K_INST];
  __shared__ int c[K_INST];
  __shared__ int selc[K_REL];
  __shared__ int sortedc[K_REL];
  const int tid = threadIdx.x;
  const int subj = inst[b * K_INST + r];
  const int rowg = b * N + subj;
  const float m = m_arr[rowg];
  const float S = s_arr[rowg];
  const float* srow = scores + (size_t)rowg * N;
  for (int e = tid; e < K_INST; e += 256) {
    int col = inst[b * K_INST + e];
    v[e] = (e == r) ? 1e9f : expf(srow[col] - m) / S;  // prob value, like ref
    c[e] = e;
  }
  __syncthreads();
  for (int k = 2; k <= K_INST; k <<= 1) {
    for (int j = k >> 1; j > 0; j >>= 1) {
      int p = tid;
      int i = 2 * p - (p & (j - 1));
      int ixj = i | j;
      float va = v[i], vb = v[ixj];
      int ia = c[i], ib = c[ixj];
      bool a_first = (va > vb) || (va == vb && ia < ib);  // descending
      bool up = ((i & k) == 0);
      if (up != a_first) { v[i] = vb; v[ixj] = va; c[i] = ib; c[ixj] = ia; }
      __syncthreads();
    }
  }
  if (tid < K_REL) selc[tid] = c[tid];
  __syncthreads();
  if (tid < K_REL) {
    int myc = selc[tid];
    int rank = 0;
#pragma unroll
    for (int p2 = 0; p2 < K_REL; p2++) rank += (selc[p2] < myc);
    sortedc[rank] = myc;
  }
  __syncthreads();
  if (tid < K_REL) {
    int cc = sortedc[tid];
    int obj = inst[b * K_INST + cc];
    size_t pidx = (size_t)b * PAIRS_PER_B + (size_t)r * K_REL + tid;
    soi_out[pidx * 3 + 0] = (float)b;
    soi_out[pidx * 3 + 1] = (float)subj;
    soi_out[pidx * 3 + 2] = (float)obj;
    pairs[pidx * 2 + 0] = subj;
    pairs[pidx * 2 + 1] = obj;
  }
}

// ---------------------------------------------------------------------------
// Kernel 5: rel_e = layernorm(q[subj] + q[obj]) over D=256, no affine.
// One 256-thread block per pair (131072 blocks).
// ---------------------------------------------------------------------------
__global__ __launch_bounds__(256)
void rel_embed(const float* __restrict__ q, const int* __restrict__ pairs,
               float* __restrict__ out) {
  const size_t p = blockIdx.x;
  const int b = (int)(p >> 14);
  const int subj = pairs[p * 2], obj = pairs[p * 2 + 1];
  const float* qs = q + ((size_t)b * N + subj) * D;
  const float* qo = q + ((size_t)b * N + obj) * D;
  const int t = threadIdx.x;
  const int lane = t & 63, wid = t >> 6;
  __shared__ float red[4];
  __shared__ float bc[2];
  float e = qs[t] + qo[t];
  float s = e;
#pragma unroll
  for (int o = 32; o > 0; o >>= 1) s += __shfl_down(s, o);
  if (lane == 0) red[wid] = s;
  __syncthreads();
  if (t == 0) bc[0] = (red[0] + red[1] + red[2] + red[3]) * (1.0f / D);
  __syncthreads();
  float mu = bc[0];
  float dv = e - mu;
  float s2 = dv * dv;
#pragma unroll
  for (int o = 32; o > 0; o >>= 1) s2 += __shfl_down(s2, o);
  if (lane == 0) red[wid] = s2;   // safe: all reads of red happened before prev barrier
  __syncthreads();
  if (t == 0) bc[1] = (red[0] + red[1] + red[2] + red[3]) * (1.0f / D);
  __syncthreads();
  float var = bc[1];
  out[p * D + t] = dv * rsqrtf(var + 1e-5f);
}

// ---------------------------------------------------------------------------
extern "C" void kernel_launch(void* const* d_in, const int* in_sizes, int n_in,
                              void* d_out, int out_size, void* d_ws, size_t ws_size,
                              hipStream_t stream) {
  const float* q = (const float*)d_in[0];
  const float* k = (const float*)d_in[1];
  float* out = (float*)d_out;

  // Output layout (flat fp32, return order): scores1, soi, rel_e
  float* scores = out;                                   // 8*2048*2048
  float* soi = out + (size_t)BATCH * N * N;              // 8*16384*3
  float* rele = soi + (size_t)BATCH * PAIRS_PER_B * 3;   // 8*16384*256

  // Workspace layout
  float* m_arr = (float*)d_ws;                 // 16384 f
  float* s_arr = m_arr + BATCH * N;            // 16384 f
  float* diag = s_arr + BATCH * N;             // 16384 f
  int* inst = (int*)(diag + BATCH * N);        // 4096 i
  int* pairs = inst + BATCH * K_INST;          // 262144 i

  gemm_qkT<<<dim3(N / BN, N / BM, BATCH), 256, 0, stream>>>(q, k, scores);
  row_stats<<<BATCH * N, 256, 0, stream>>>(scores, m_arr, s_arr, diag);
  topk_inst<<<BATCH, 256, 0, stream>>>(diag, inst);
  rel_topk<<<BATCH * K_INST, 256, 0, stream>>>(scores, m_arr, s_arr, inst, soi, pairs);
  rel_embed<<<BATCH * PAIRS_PER_B, 256, 0, stream>>>(q, pairs, rele);
}